// Round 1
// baseline (1189.435 us; speedup 1.0000x reference)
//
#include <hip/hip_runtime.h>
#include <math.h>

#define BATCH 8
#define N_ANCH 76725
#define NCLS 80
#define NDET 100
#define NPRED 84
#define NMS_T 512
#define NMS_W (NMS_T / 64)

// ---------------------------------------------------------------------------
// K1: per-anchor class argmax (on sigmoid(conf), first-occurrence) + score,
//     plus per-batch class histogram.
// ---------------------------------------------------------------------------
__global__ void k_decode_cls(const float* __restrict__ pred,
                             float* __restrict__ d_score,
                             int* __restrict__ d_cls,
                             int* __restrict__ g_counts) {
  __shared__ int hist[BATCH * NCLS];
  for (int k = threadIdx.x; k < BATCH * NCLS; k += blockDim.x) hist[k] = 0;
  __syncthreads();

  int gid = blockIdx.x * blockDim.x + threadIdx.x;
  if (gid < BATCH * N_ANCH) {
    int b = gid / N_ANCH;
    const float4* row = (const float4*)(pred + (size_t)gid * NPRED);
    float best = -INFINITY;
    int bc = 0;
    for (int q = 1; q < 21; ++q) {
      float4 v = row[q];
      float c;
      c = 1.0f / (1.0f + expf(-v.x));
      if (c > best) { best = c; bc = q * 4 - 4; }
      c = 1.0f / (1.0f + expf(-v.y));
      if (c > best) { best = c; bc = q * 4 - 3; }
      c = 1.0f / (1.0f + expf(-v.z));
      if (c > best) { best = c; bc = q * 4 - 2; }
      c = 1.0f / (1.0f + expf(-v.w));
      if (c > best) { best = c; bc = q * 4 - 1; }
    }
    d_score[gid] = (best > 0.05f) ? best : -1.0f;
    d_cls[gid] = bc;
    atomicAdd(&hist[b * NCLS + bc], 1);
  }
  __syncthreads();
  for (int k = threadIdx.x; k < BATCH * NCLS; k += blockDim.x)
    if (hist[k]) atomicAdd(&g_counts[k], hist[k]);
}

// ---------------------------------------------------------------------------
// K2: exclusive scan of class counts -> bucket starts + scatter cursors.
// ---------------------------------------------------------------------------
__global__ void k_scan(const int* __restrict__ g_counts,
                       int* __restrict__ g_starts,
                       int* __restrict__ g_cursor) {
  int b = threadIdx.x;
  if (b < BATCH) {
    int run = 0;
    for (int c = 0; c < NCLS; ++c) {
      int cnt = g_counts[b * NCLS + c];
      g_starts[b * NCLS + c] = run;
      g_cursor[b * NCLS + c] = run;
      run += cnt;
    }
  }
}

// ---------------------------------------------------------------------------
// K3: scatter anchors into class buckets (SoA: score, orig idx, corners_off).
//     Box decode replicates reference op order; fp contract off so mul+add
//     doesn't fuse into fma (reference computes them separately).
// ---------------------------------------------------------------------------
__global__ void k_scatter(const float* __restrict__ pred,
                          const float* __restrict__ anchors,
                          const float* __restrict__ d_score,
                          const int* __restrict__ d_cls,
                          int* __restrict__ g_cursor,
                          float* __restrict__ bs_score,
                          int* __restrict__ bs_oidx,
                          float* __restrict__ bs_c0, float* __restrict__ bs_c1,
                          float* __restrict__ bs_c2, float* __restrict__ bs_c3) {
#pragma clang fp contract(off)
  int gid = blockIdx.x * blockDim.x + threadIdx.x;
  if (gid >= BATCH * N_ANCH) return;
  int b = gid / N_ANCH;
  int i = gid - b * N_ANCH;
  int c = d_cls[gid];
  float s = d_score[gid];
  float4 bp = *(const float4*)(pred + (size_t)gid * NPRED);
  float4 a = *(const float4*)(anchors + (size_t)i * 4);
  float b0 = bp.x * 0.1f, b1 = bp.y * 0.1f, b2 = bp.z * 0.2f, b3 = bp.w * 0.2f;
  float cx = b0 * a.z + a.x;
  float cy = b1 * a.w + a.y;
  float w = expf(b2) * a.z;
  float h = expf(b3) * a.w;
  float x0 = cx - 0.5f * w, y0 = cy - 0.5f * h;
  float x1 = cx + 0.5f * w, y1 = cy + 0.5f * h;
  float off = (float)c * 10000.0f;
  int pos = atomicAdd(&g_cursor[b * NCLS + c], 1);
  int slot = b * N_ANCH + pos;
  bs_score[slot] = s;
  bs_oidx[slot] = i;
  bs_c0[slot] = x0 + off;
  bs_c1[slot] = y0 + off;
  bs_c2[slot] = x1 + off;
  bs_c3[slot] = y1 + off;
}

// ---------------------------------------------------------------------------
// K4: exact iterative NMS, one block per batch. Per-class running maxima in
//     LDS; each iteration: lexmax over 80 class maxima (score desc, orig idx
//     asc — matches jnp.argmax first-max), then fused suppress+recompute of
//     the selected class's bucket only (cross-class IoU is provably 0).
// ---------------------------------------------------------------------------
__global__ void __launch_bounds__(NMS_T) k_nms(
    const float* __restrict__ pred, const float* __restrict__ anchors,
    const int* __restrict__ g_starts, const int* __restrict__ g_counts,
    float* __restrict__ bs_score, const int* __restrict__ bs_oidx,
    const float* __restrict__ bs_c0, const float* __restrict__ bs_c1,
    const float* __restrict__ bs_c2, const float* __restrict__ bs_c3,
    float* __restrict__ out) {
#pragma clang fp contract(off)
  const int b = blockIdx.x;
  const int tid = threadIdx.x;
  const int wid = tid >> 6;
  const int lid = tid & 63;

  __shared__ int s_start[NCLS];
  __shared__ int s_cnt[NCLS];
  __shared__ float cm_s[NCLS];
  __shared__ int cm_oi[NCLS];
  __shared__ int cm_p[NCLS];
  __shared__ float red_s[NMS_W];
  __shared__ int red_oi[NMS_W], red_p[NMS_W], red_c[NMS_W];
  __shared__ float sh_best_s;
  __shared__ int sh_best_oi, sh_best_p, sh_best_c;

  for (int k = tid; k < NCLS; k += NMS_T) {
    s_start[k] = g_starts[b * NCLS + k];
    s_cnt[k] = g_counts[b * NCLS + k];
  }
  __syncthreads();

  // Init per-class maxima: one wave per class, round-robin.
  for (int c = wid; c < NCLS; c += NMS_W) {
    int st = s_start[c], cnt = s_cnt[c];
    int base = b * N_ANCH + st;
    float ms = -INFINITY;
    int moi = 0x7fffffff, mp = -1;
    for (int j = lid; j < cnt; j += 64) {
      float sv = bs_score[base + j];
      int oiv = bs_oidx[base + j];
      if (sv > ms || (sv == ms && oiv < moi)) { ms = sv; moi = oiv; mp = base + j; }
    }
    for (int off = 32; off; off >>= 1) {
      float os = __shfl_down(ms, off);
      int ooi = __shfl_down(moi, off);
      int op = __shfl_down(mp, off);
      if (os > ms || (os == ms && ooi < moi)) { ms = os; moi = ooi; mp = op; }
    }
    if (lid == 0) { cm_s[c] = ms; cm_oi[c] = moi; cm_p[c] = mp; }
  }
  __syncthreads();

  for (int t = 0; t < NDET; ++t) {
    // ---- global argmax over the 80 class maxima ----
    float ms = -INFINITY;
    int moi = 0x7fffffff, mp = -1, mc = -1;
    if (tid < NCLS) { ms = cm_s[tid]; moi = cm_oi[tid]; mp = cm_p[tid]; mc = tid; }
    for (int off = 32; off; off >>= 1) {
      float os = __shfl_down(ms, off);
      int ooi = __shfl_down(moi, off);
      int op = __shfl_down(mp, off);
      int oc = __shfl_down(mc, off);
      if (os > ms || (os == ms && ooi < moi)) { ms = os; moi = ooi; mp = op; mc = oc; }
    }
    if (lid == 0) { red_s[wid] = ms; red_oi[wid] = moi; red_p[wid] = mp; red_c[wid] = mc; }
    __syncthreads();
    if (tid == 0) {
      float bs2 = red_s[0];
      int boi = red_oi[0], bp2 = red_p[0], bc2 = red_c[0];
      for (int w = 1; w < NMS_W; ++w) {
        if (red_s[w] > bs2 || (red_s[w] == bs2 && red_oi[w] < boi)) {
          bs2 = red_s[w]; boi = red_oi[w]; bp2 = red_p[w]; bc2 = red_c[w];
        }
      }
      sh_best_s = bs2; sh_best_oi = boi; sh_best_p = bp2; sh_best_c = bc2;
    }
    __syncthreads();
    float bsv = sh_best_s;
    int p = sh_best_p, c = sh_best_c, oi = sh_best_oi;

    if (!(bsv > 0.0f)) {
      // All remaining scores <= 0 forever: emit empty dets and stop.
      float* o = out + (size_t)(b * NDET + t) * 6;
      int total = (NDET - t) * 6;
      for (int k = tid; k < total; k += NMS_T) o[k] = ((k % 6) >= 4) ? -1.0f : 0.0f;
      return;
    }

    if (tid == 0) {
      // Re-derive boxes_xywh[idx] from predictions + anchor (reference math).
      const float* pr = pred + ((size_t)b * N_ANCH + oi) * NPRED;
      const float* a = anchors + (size_t)oi * 4;
      float b0 = pr[0] * 0.1f, b1 = pr[1] * 0.1f, b2 = pr[2] * 0.2f, b3 = pr[3] * 0.2f;
      float cx = b0 * a[2] + a[0];
      float cy = b1 * a[3] + a[1];
      float w = expf(b2) * a[2];
      float h = expf(b3) * a[3];
      float* o = out + (size_t)(b * NDET + t) * 6;
      o[0] = cx; o[1] = cy; o[2] = w; o[3] = h; o[4] = (float)c; o[5] = bsv;
    }

    // ---- fused suppress + class-max recompute over bucket c only ----
    float pc0 = bs_c0[p], pc1 = bs_c1[p], pc2 = bs_c2[p], pc3 = bs_c3[p];
    float pa = (pc2 - pc0) * (pc3 - pc1);
    int st = s_start[c], cnt = s_cnt[c];
    int base = b * N_ANCH + st;
    float ns = -INFINITY;
    int noi = 0x7fffffff, np2 = -1;
    for (int j = tid; j < cnt; j += NMS_T) {
      int slot = base + j;
      float c0 = bs_c0[slot], c1 = bs_c1[slot], c2 = bs_c2[slot], c3 = bs_c3[slot];
      float lx = fmaxf(pc0, c0), ly = fmaxf(pc1, c1);
      float rx = fminf(pc2, c2), ry = fminf(pc3, c3);
      float ww = fmaxf(rx - lx, 0.0f), hh = fmaxf(ry - ly, 0.0f);
      float inter = ww * hh;
      float a2 = (c2 - c0) * (c3 - c1);
      float iou = inter / (pa + a2 - inter + 1e-8f);
      float sv = bs_score[slot];
      if (iou > 0.5f) { sv = -1.0f; bs_score[slot] = -1.0f; }  // includes slot==p
      int oiv = bs_oidx[slot];
      if (sv > ns || (sv == ns && oiv < noi)) { ns = sv; noi = oiv; np2 = slot; }
    }
    for (int off = 32; off; off >>= 1) {
      float os = __shfl_down(ns, off);
      int ooi = __shfl_down(noi, off);
      int op = __shfl_down(np2, off);
      if (os > ns || (os == ns && ooi < noi)) { ns = os; noi = ooi; np2 = op; }
    }
    if (lid == 0) { red_s[wid] = ns; red_oi[wid] = noi; red_p[wid] = np2; }
    __syncthreads();
    if (tid == 0) {
      float bs2 = red_s[0];
      int boi = red_oi[0], bp2 = red_p[0];
      for (int w = 1; w < NMS_W; ++w) {
        if (red_s[w] > bs2 || (red_s[w] == bs2 && red_oi[w] < boi)) {
          bs2 = red_s[w]; boi = red_oi[w]; bp2 = red_p[w];
        }
      }
      cm_s[c] = bs2; cm_oi[c] = boi; cm_p[c] = bp2;
    }
    __syncthreads();
  }
}

// ---------------------------------------------------------------------------
extern "C" void kernel_launch(void* const* d_in, const int* in_sizes, int n_in,
                              void* d_out, int out_size, void* d_ws, size_t ws_size,
                              hipStream_t stream) {
  const float* pred = (const float*)d_in[1];     // (8, 76725, 84) f32
  const float* anchors = (const float*)d_in[2];  // (76725, 4) f32
  float* out = (float*)d_out;                    // (8, 100, 6) f32

  const size_t BN = (size_t)BATCH * N_ANCH;
  float* ws = (float*)d_ws;
  float* d_score = ws;               ws += BN;
  int*   d_cls   = (int*)ws;         ws += BN;
  float* bs_score = ws;              ws += BN;
  int*   bs_oidx  = (int*)ws;        ws += BN;
  float* bs_c0 = ws;                 ws += BN;
  float* bs_c1 = ws;                 ws += BN;
  float* bs_c2 = ws;                 ws += BN;
  float* bs_c3 = ws;                 ws += BN;
  int* g_counts = (int*)ws;          ws += BATCH * NCLS;
  int* g_starts = (int*)ws;          ws += BATCH * NCLS;
  int* g_cursor = (int*)ws;          ws += BATCH * NCLS;

  hipMemsetAsync(g_counts, 0, BATCH * NCLS * sizeof(int), stream);

  int nb = (int)((BN + 255) / 256);
  k_decode_cls<<<nb, 256, 0, stream>>>(pred, d_score, d_cls, g_counts);
  k_scan<<<1, 64, 0, stream>>>(g_counts, g_starts, g_cursor);
  k_scatter<<<nb, 256, 0, stream>>>(pred, anchors, d_score, d_cls, g_cursor,
                                    bs_score, bs_oidx, bs_c0, bs_c1, bs_c2, bs_c3);
  k_nms<<<BATCH, NMS_T, 0, stream>>>(pred, anchors, g_starts, g_counts,
                                     bs_score, bs_oidx, bs_c0, bs_c1, bs_c2, bs_c3,
                                     out);
}